// Round 1
// baseline (1652.892 us; speedup 1.0000x reference)
//
#include <hip/hip_runtime.h>

#define NN 50000
#define EE 600000

__device__ inline void fma4(float4& a, float s, const float4 w) {
  a.x = fmaf(s, w.x, a.x);
  a.y = fmaf(s, w.y, a.y);
  a.z = fmaf(s, w.z, a.z);
  a.w = fmaf(s, w.w, a.w);
}

// ---------- CSR build ----------
__global__ void count_k(const int* __restrict__ ei, int* __restrict__ cnt) {
  int e = blockIdx.x * 256 + threadIdx.x;
  if (e < EE) atomicAdd(&cnt[ei[EE + e]], 1);
}

__global__ void scan_k(const int* __restrict__ cnt, int* __restrict__ rs) {
  __shared__ int ls[1024];
  const int t = threadIdx.x;
  const int STRIP = (NN + 1023) >> 10;  // 49
  int i0 = t * STRIP;
  int i1 = min(i0 + STRIP, NN);
  int s = 0;
  for (int i = i0; i < i1; ++i) s += cnt[i];
  ls[t] = s;
  __syncthreads();
  for (int off = 1; off < 1024; off <<= 1) {
    int v = (t >= off) ? ls[t - off] : 0;
    __syncthreads();
    ls[t] += v;
    __syncthreads();
  }
  int run = (t == 0) ? 0 : ls[t - 1];
  for (int i = i0; i < i1; ++i) { rs[i] = run; run += cnt[i]; }
  if (t == 0) rs[NN] = EE;
}

__global__ void fill_k(const int* __restrict__ ei, const float* __restrict__ ew,
                       int* __restrict__ cur, int* __restrict__ srcb,
                       float* __restrict__ wb) {
  int e = blockIdx.x * 256 + threadIdx.x;
  if (e < EE) {
    int d = ei[EE + e];
    int p = atomicAdd(&cur[d], 1);
    srcb[p] = ei[e];
    wb[p] = ew[e];
  }
}

// ---------- fused dual GEMM: Tl = bnrelu(H)@Wl, Tr = bnrelu(H)@Wr ----------
// K = 128 fixed. F = per-matrix output cols (128 or 64).
// ss = {scale[128], shift[128]} applied with relu during staging, or null.
template <int F>
__global__ __launch_bounds__(256, 3) void gemm_dual(
    const float* __restrict__ H, const float* __restrict__ Wl,
    const float* __restrict__ Wr, const float* __restrict__ ss,
    float* __restrict__ Tl, float* __restrict__ Tr) {
  constexpr int K = 128;
  constexpr int Kc = 32;
  constexpr int TX = F / 4;       // 32 or 16 col-groups
  constexpr int TY = 256 / TX;    // 8 or 16
  constexpr int ROWS = TY * 8;    // 64 or 128 rows per block
  constexpr int HS = ROWS + 4;    // padded (multiple of 4 keeps 16B align)
  __shared__ __align__(16) float Wls[Kc][F];
  __shared__ __align__(16) float Wrs[Kc][F];
  __shared__ __align__(16) float Hs[Kc][HS];
  const int tid = threadIdx.x;
  const int tx = tid % TX, ty = tid / TX;
  const int n0 = blockIdx.x * ROWS;

  const float4 z4 = {0.f, 0.f, 0.f, 0.f};
  float4 aAA[4], aAB[4], aBA[4], aBB[4];
#pragma unroll
  for (int r = 0; r < 4; ++r) { aAA[r] = z4; aAB[r] = z4; aBA[r] = z4; aBB[r] = z4; }

  for (int kc = 0; kc < K; kc += Kc) {
    __syncthreads();
    // stage weights (coalesced, conflict-free f4 LDS writes)
    for (int idx = tid; idx < Kc * (F / 4); idx += 256) {
      int k = idx / (F / 4), c = idx % (F / 4);
      ((float4*)(&Wls[k][0]))[c] = ((const float4*)Wl)[(kc + k) * (F / 4) + c];
      ((float4*)(&Wrs[k][0]))[c] = ((const float4*)Wr)[(kc + k) * (F / 4) + c];
    }
    // stage H transposed (k-major) with fused BN+ReLU
    for (int idx = tid; idx < ROWS * 8; idx += 256) {
      int i = idx >> 3, k4 = idx & 7;
      int nrow = n0 + i;
      float4 hv = z4;
      if (nrow < NN) hv = ((const float4*)H)[nrow * 32 + (kc >> 2) + k4];
      if (ss) {
        int gk = kc + k4 * 4;
        hv.x = fmaxf(fmaf(hv.x, ss[gk + 0], ss[128 + gk + 0]), 0.f);
        hv.y = fmaxf(fmaf(hv.y, ss[gk + 1], ss[128 + gk + 1]), 0.f);
        hv.z = fmaxf(fmaf(hv.z, ss[gk + 2], ss[128 + gk + 2]), 0.f);
        hv.w = fmaxf(fmaf(hv.w, ss[gk + 3], ss[128 + gk + 3]), 0.f);
      }
      Hs[k4 * 4 + 0][i] = hv.x;
      Hs[k4 * 4 + 1][i] = hv.y;
      Hs[k4 * 4 + 2][i] = hv.z;
      Hs[k4 * 4 + 3][i] = hv.w;
    }
    __syncthreads();
#pragma unroll 4
    for (int k = 0; k < Kc; ++k) {
      float4 wA = *(const float4*)&Wls[k][tx * 4];
      float4 wB = *(const float4*)&Wrs[k][tx * 4];
      float4 hA = *(const float4*)&Hs[k][ty * 4];
      float4 hB = *(const float4*)&Hs[k][ROWS / 2 + ty * 4];
      fma4(aAA[0], hA.x, wA); fma4(aAA[1], hA.y, wA); fma4(aAA[2], hA.z, wA); fma4(aAA[3], hA.w, wA);
      fma4(aAB[0], hA.x, wB); fma4(aAB[1], hA.y, wB); fma4(aAB[2], hA.z, wB); fma4(aAB[3], hA.w, wB);
      fma4(aBA[0], hB.x, wA); fma4(aBA[1], hB.y, wA); fma4(aBA[2], hB.z, wA); fma4(aBA[3], hB.w, wA);
      fma4(aBB[0], hB.x, wB); fma4(aBB[1], hB.y, wB); fma4(aBB[2], hB.z, wB); fma4(aBB[3], hB.w, wB);
    }
  }
  float4* Tl4 = (float4*)Tl;
  float4* Tr4 = (float4*)Tr;
#pragma unroll
  for (int r = 0; r < 4; ++r) {
    int nA = n0 + ty * 4 + r;
    if (nA < NN) { Tl4[nA * TX + tx] = aAA[r]; Tr4[nA * TX + tx] = aAB[r]; }
    int nB = n0 + ROWS / 2 + ty * 4 + r;
    if (nB < NN) { Tl4[nB * TX + tx] = aBA[r]; Tr4[nB * TX + tx] = aBB[r]; }
  }
}

// ---------- CSR gather + combine (+optional BN stats) ----------
// out[n] = (sum_{e->n} w_e * Tl[src_e]) / max(deg,1) + Tr[n] + bias
template <int F4, bool STATS>
__global__ __launch_bounds__(256, 4) void gather_combine(
    const float* __restrict__ Tl, const float* __restrict__ Tr,
    const int* __restrict__ rs, const int* __restrict__ srcb,
    const float* __restrict__ wb, const float* __restrict__ bias,
    float* __restrict__ out, float* __restrict__ stats) {
  constexpr int NODES = 256 / F4;
  const int tid = threadIdx.x;
  const int c = tid % F4;
  const int ni = tid / F4;
  const int n = blockIdx.x * NODES + ni;
  const float4* Tl4 = (const float4*)Tl;
  const float4* Tr4 = (const float4*)Tr;
  const float4* b4 = (const float4*)bias;
  float4 v = {0.f, 0.f, 0.f, 0.f};
  if (n < NN) {
    int r0 = rs[n], r1 = rs[n + 1];
    float4 acc = {0.f, 0.f, 0.f, 0.f};
    for (int j = r0; j < r1; ++j) {
      int s = srcb[j];
      float w = wb[j];
      float4 tv = Tl4[s * F4 + c];
      fma4(acc, w, tv);
    }
    float inv = 1.0f / fmaxf((float)(r1 - r0), 1.0f);
    float4 t = Tr4[n * F4 + c];
    float4 bb = b4[c];
    v.x = fmaf(acc.x, inv, t.x + bb.x);
    v.y = fmaf(acc.y, inv, t.y + bb.y);
    v.z = fmaf(acc.z, inv, t.z + bb.z);
    v.w = fmaf(acc.w, inv, t.w + bb.w);
    ((float4*)out)[n * F4 + c] = v;
  }
  if constexpr (STATS) {  // only instantiated with F4=32 (2 nodes per wave)
    __shared__ float4 redS[4][32];
    __shared__ float4 redQ[4][32];
    float4 q;
    q.x = v.x * v.x; q.y = v.y * v.y; q.z = v.z * v.z; q.w = v.w * v.w;
    float4 s = v;
    s.x += __shfl_xor(s.x, 32, 64); s.y += __shfl_xor(s.y, 32, 64);
    s.z += __shfl_xor(s.z, 32, 64); s.w += __shfl_xor(s.w, 32, 64);
    q.x += __shfl_xor(q.x, 32, 64); q.y += __shfl_xor(q.y, 32, 64);
    q.z += __shfl_xor(q.z, 32, 64); q.w += __shfl_xor(q.w, 32, 64);
    const int lane = tid & 63, wid = tid >> 6;
    if (lane < 32) { redS[wid][lane] = s; redQ[wid][lane] = q; }
    __syncthreads();
    if (tid < 32) {
      float4 S = redS[0][tid];
      float4 Q = redQ[0][tid];
#pragma unroll
      for (int w2 = 1; w2 < 4; ++w2) {
        S.x += redS[w2][tid].x; S.y += redS[w2][tid].y;
        S.z += redS[w2][tid].z; S.w += redS[w2][tid].w;
        Q.x += redQ[w2][tid].x; Q.y += redQ[w2][tid].y;
        Q.z += redQ[w2][tid].z; Q.w += redQ[w2][tid].w;
      }
      atomicAdd(&stats[tid * 4 + 0], S.x); atomicAdd(&stats[tid * 4 + 1], S.y);
      atomicAdd(&stats[tid * 4 + 2], S.z); atomicAdd(&stats[tid * 4 + 3], S.w);
      atomicAdd(&stats[128 + tid * 4 + 0], Q.x); atomicAdd(&stats[128 + tid * 4 + 1], Q.y);
      atomicAdd(&stats[128 + tid * 4 + 2], Q.z); atomicAdd(&stats[128 + tid * 4 + 3], Q.w);
    }
  }
}

// ---------- BN finalize: scale/shift from accumulated stats ----------
__global__ void bn_fin(const float* __restrict__ stats, const float* __restrict__ gamma,
                       const float* __restrict__ beta, float* __restrict__ ss) {
  int f = threadIdx.x;
  float mu = stats[f] * (1.0f / (float)NN);
  float ex2 = stats[128 + f] * (1.0f / (float)NN);
  float var = ex2 - mu * mu;
  float sc = gamma[f] * rsqrtf(var + 1e-5f);
  ss[f] = sc;
  ss[128 + f] = beta[f] - mu * sc;
}

extern "C" void kernel_launch(void* const* d_in, const int* in_sizes, int n_in,
                              void* d_out, int out_size, void* d_ws, size_t ws_size,
                              hipStream_t stream) {
  (void)in_sizes; (void)n_in; (void)out_size; (void)ws_size;
  const float* x   = (const float*)d_in[0];
  const int*   ei  = (const int*)d_in[1];
  const float* ew  = (const float*)d_in[2];
  const float* Wl0 = (const float*)d_in[3];
  const float* Wr0 = (const float*)d_in[4];
  const float* b0  = (const float*)d_in[5];
  const float* Wl1 = (const float*)d_in[6];
  const float* Wr1 = (const float*)d_in[7];
  const float* b1  = (const float*)d_in[8];
  const float* Wl2 = (const float*)d_in[9];
  const float* Wr2 = (const float*)d_in[10];
  const float* b2  = (const float*)d_in[11];
  const float* g0  = (const float*)d_in[12];
  const float* be0 = (const float*)d_in[13];
  const float* g1  = (const float*)d_in[14];
  const float* be1 = (const float*)d_in[15];
  float* out = (float*)d_out;

  size_t off = 0;
  auto alloc = [&](size_t b) -> void* {
    void* p = (char*)d_ws + off;
    off += (b + 255) & ~(size_t)255;
    return p;
  };
  float* tl    = (float*)alloc((size_t)NN * 128 * 4);   // 25.6 MB
  float* tr    = (float*)alloc((size_t)NN * 128 * 4);   // 25.6 MB
  float* hpre  = (float*)alloc((size_t)NN * 128 * 4);   // 25.6 MB
  int*   srcb  = (int*)alloc((size_t)EE * 4);           // 2.4 MB
  float* wb    = (float*)alloc((size_t)EE * 4);         // 2.4 MB
  int*   rs    = (int*)alloc((size_t)(NN + 1) * 4);
  int*   cur   = (int*)alloc((size_t)NN * 4);
  float* stats = (float*)alloc(256 * 4);
  float* ssb   = (float*)alloc(256 * 4);

  // CSR build (per call; inputs are re-poisoned each launch)
  hipMemsetAsync(cur, 0, (size_t)NN * 4, stream);
  count_k<<<(EE + 255) / 256, 256, 0, stream>>>(ei, cur);
  scan_k<<<1, 1024, 0, stream>>>(cur, rs);
  hipMemcpyAsync(cur, rs, (size_t)NN * 4, hipMemcpyDeviceToDevice, stream);
  fill_k<<<(EE + 255) / 256, 256, 0, stream>>>(ei, ew, cur, srcb, wb);

  // layer 0: input x, no BN on input
  gemm_dual<128><<<(NN + 63) / 64, 256, 0, stream>>>(x, Wl0, Wr0, nullptr, tl, tr);
  hipMemsetAsync(stats, 0, 256 * 4, stream);
  gather_combine<32, true><<<NN / 8, 256, 0, stream>>>(tl, tr, rs, srcb, wb, b0, hpre, stats);
  bn_fin<<<1, 128, 0, stream>>>(stats, g0, be0, ssb);

  // layer 1: BN0+ReLU folded into GEMM staging
  gemm_dual<128><<<(NN + 63) / 64, 256, 0, stream>>>(hpre, Wl1, Wr1, ssb, tl, tr);
  hipMemsetAsync(stats, 0, 256 * 4, stream);
  gather_combine<32, true><<<NN / 8, 256, 0, stream>>>(tl, tr, rs, srcb, wb, b1, hpre, stats);
  bn_fin<<<1, 128, 0, stream>>>(stats, g1, be1, ssb);

  // layer 2: BN1+ReLU folded into GEMM staging, output F=64 straight to d_out
  gemm_dual<64><<<(NN + 127) / 128, 256, 0, stream>>>(hpre, Wl2, Wr2, ssb, tl, tr);
  gather_combine<16, false><<<NN / 16, 256, 0, stream>>>(tl, tr, rs, srcb, wb, b2, out, nullptr);
}

// Round 2
// 1624.449 us; speedup vs baseline: 1.0175x; 1.0175x over previous
//
#include <hip/hip_runtime.h>

#define NN 50000
#define EE 600000

__device__ inline void fma4(float4& a, float s, const float4 w) {
  a.x = fmaf(s, w.x, a.x);
  a.y = fmaf(s, w.y, a.y);
  a.z = fmaf(s, w.z, a.z);
  a.w = fmaf(s, w.w, a.w);
}

// ---------- CSR build ----------
__global__ void count_k(const int* __restrict__ ei, int* __restrict__ cnt) {
  int e = blockIdx.x * 256 + threadIdx.x;
  if (e < EE) atomicAdd(&cnt[ei[EE + e]], 1);
}

__global__ void scan_k(const int* __restrict__ cnt, int* __restrict__ rs) {
  __shared__ int ls[1024];
  const int t = threadIdx.x;
  const int STRIP = (NN + 1023) >> 10;  // 49
  int i0 = t * STRIP;
  int i1 = min(i0 + STRIP, NN);
  int s = 0;
  for (int i = i0; i < i1; ++i) s += cnt[i];
  ls[t] = s;
  __syncthreads();
  for (int off = 1; off < 1024; off <<= 1) {
    int v = (t >= off) ? ls[t - off] : 0;
    __syncthreads();
    ls[t] += v;
    __syncthreads();
  }
  int run = (t == 0) ? 0 : ls[t - 1];
  for (int i = i0; i < i1; ++i) { rs[i] = run; run += cnt[i]; }
  if (t == 0) rs[NN] = EE;
}

// packs (src, weight-bits) adjacent so the gather loop does one 8B load/edge
__global__ void fill_k(const int* __restrict__ ei, const float* __restrict__ ew,
                       int* __restrict__ cur, int2* __restrict__ esw) {
  int e = blockIdx.x * 256 + threadIdx.x;
  if (e < EE) {
    int d = ei[EE + e];
    int p = atomicAdd(&cur[d], 1);
    int2 v;
    v.x = ei[e];
    v.y = __float_as_int(ew[e]);
    esw[p] = v;
  }
}

// ---------- fused dual GEMM: Tl = bnrelu(H)@Wl, Tr = bnrelu(H)@Wr ----------
template <int F>
__global__ __launch_bounds__(256, 3) void gemm_dual(
    const float* __restrict__ H, const float* __restrict__ Wl,
    const float* __restrict__ Wr, const float* __restrict__ ss,
    float* __restrict__ Tl, float* __restrict__ Tr) {
  constexpr int K = 128;
  constexpr int Kc = 32;
  constexpr int TX = F / 4;       // 32 or 16 col-groups
  constexpr int TY = 256 / TX;    // 8 or 16
  constexpr int ROWS = TY * 8;    // 64 or 128 rows per block
  constexpr int HS = ROWS + 4;    // padded (multiple of 4 keeps 16B align)
  __shared__ __align__(16) float Wls[Kc][F];
  __shared__ __align__(16) float Wrs[Kc][F];
  __shared__ __align__(16) float Hs[Kc][HS];
  const int tid = threadIdx.x;
  const int tx = tid % TX, ty = tid / TX;
  const int n0 = blockIdx.x * ROWS;

  const float4 z4 = {0.f, 0.f, 0.f, 0.f};
  float4 aAA[4], aAB[4], aBA[4], aBB[4];
#pragma unroll
  for (int r = 0; r < 4; ++r) { aAA[r] = z4; aAB[r] = z4; aBA[r] = z4; aBB[r] = z4; }

  for (int kc = 0; kc < K; kc += Kc) {
    __syncthreads();
    for (int idx = tid; idx < Kc * (F / 4); idx += 256) {
      int k = idx / (F / 4), c = idx % (F / 4);
      ((float4*)(&Wls[k][0]))[c] = ((const float4*)Wl)[(kc + k) * (F / 4) + c];
      ((float4*)(&Wrs[k][0]))[c] = ((const float4*)Wr)[(kc + k) * (F / 4) + c];
    }
    for (int idx = tid; idx < ROWS * 8; idx += 256) {
      int i = idx >> 3, k4 = idx & 7;
      int nrow = n0 + i;
      float4 hv = z4;
      if (nrow < NN) hv = ((const float4*)H)[nrow * 32 + (kc >> 2) + k4];
      if (ss) {
        int gk = kc + k4 * 4;
        hv.x = fmaxf(fmaf(hv.x, ss[gk + 0], ss[128 + gk + 0]), 0.f);
        hv.y = fmaxf(fmaf(hv.y, ss[gk + 1], ss[128 + gk + 1]), 0.f);
        hv.z = fmaxf(fmaf(hv.z, ss[gk + 2], ss[128 + gk + 2]), 0.f);
        hv.w = fmaxf(fmaf(hv.w, ss[gk + 3], ss[128 + gk + 3]), 0.f);
      }
      Hs[k4 * 4 + 0][i] = hv.x;
      Hs[k4 * 4 + 1][i] = hv.y;
      Hs[k4 * 4 + 2][i] = hv.z;
      Hs[k4 * 4 + 3][i] = hv.w;
    }
    __syncthreads();
#pragma unroll 4
    for (int k = 0; k < Kc; ++k) {
      float4 wA = *(const float4*)&Wls[k][tx * 4];
      float4 wB = *(const float4*)&Wrs[k][tx * 4];
      float4 hA = *(const float4*)&Hs[k][ty * 4];
      float4 hB = *(const float4*)&Hs[k][ROWS / 2 + ty * 4];
      fma4(aAA[0], hA.x, wA); fma4(aAA[1], hA.y, wA); fma4(aAA[2], hA.z, wA); fma4(aAA[3], hA.w, wA);
      fma4(aAB[0], hA.x, wB); fma4(aAB[1], hA.y, wB); fma4(aAB[2], hA.z, wB); fma4(aAB[3], hA.w, wB);
      fma4(aBA[0], hB.x, wA); fma4(aBA[1], hB.y, wA); fma4(aBA[2], hB.z, wA); fma4(aBA[3], hB.w, wA);
      fma4(aBB[0], hB.x, wB); fma4(aBB[1], hB.y, wB); fma4(aBB[2], hB.z, wB); fma4(aBB[3], hB.w, wB);
    }
  }
  float4* Tl4 = (float4*)Tl;
  float4* Tr4 = (float4*)Tr;
#pragma unroll
  for (int r = 0; r < 4; ++r) {
    int nA = n0 + ty * 4 + r;
    if (nA < NN) { Tl4[nA * TX + tx] = aAA[r]; Tr4[nA * TX + tx] = aAB[r]; }
    int nB = n0 + ROWS / 2 + ty * 4 + r;
    if (nB < NN) { Tl4[nB * TX + tx] = aBA[r]; Tr4[nB * TX + tx] = aBB[r]; }
  }
}

// ---------- CSR gather + combine (+optional BN stats) ----------
// Edge loop chunked by 8: all (src,w) loads issue, then all 8 row-gathers
// issue, then one wait + 8 fma groups — MLP ~8 instead of 1.
template <int F4, bool STATS>
__global__ __launch_bounds__(256, 4) void gather_combine(
    const float* __restrict__ Tl, const float* __restrict__ Tr,
    const int* __restrict__ rs, const int2* __restrict__ esw,
    const float* __restrict__ bias,
    float* __restrict__ out, float* __restrict__ stats) {
  constexpr int NODES = 256 / F4;
  constexpr int CH = 8;
  const int tid = threadIdx.x;
  const int c = tid % F4;
  const int ni = tid / F4;
  const int n = blockIdx.x * NODES + ni;
  const float4* Tl4 = (const float4*)Tl;
  const float4* Tr4 = (const float4*)Tr;
  const float4* b4 = (const float4*)bias;
  float4 v = {0.f, 0.f, 0.f, 0.f};
  if (n < NN) {
    int r0 = rs[n], r1 = rs[n + 1];
    float4 acc = {0.f, 0.f, 0.f, 0.f};
    for (int j0 = r0; j0 < r1; j0 += CH) {
      int s[CH];
      float w[CH];
#pragma unroll
      for (int u = 0; u < CH; ++u) {
        int jj = (j0 + u < r1) ? (j0 + u) : r0;  // clamp; weight forced 0
        int2 p = esw[jj];
        s[u] = p.x;
        w[u] = (j0 + u < r1) ? __int_as_float(p.y) : 0.f;
      }
      float4 t[CH];
#pragma unroll
      for (int u = 0; u < CH; ++u) t[u] = Tl4[(size_t)s[u] * F4 + c];
#pragma unroll
      for (int u = 0; u < CH; ++u) fma4(acc, w[u], t[u]);
    }
    float inv = 1.0f / fmaxf((float)(r1 - r0), 1.0f);
    float4 t = Tr4[n * F4 + c];
    float4 bb = b4[c];
    v.x = fmaf(acc.x, inv, t.x + bb.x);
    v.y = fmaf(acc.y, inv, t.y + bb.y);
    v.z = fmaf(acc.z, inv, t.z + bb.z);
    v.w = fmaf(acc.w, inv, t.w + bb.w);
    ((float4*)out)[n * F4 + c] = v;
  }
  if constexpr (STATS) {  // only instantiated with F4=32 (2 nodes per wave)
    __shared__ float4 redS[4][32];
    __shared__ float4 redQ[4][32];
    float4 q;
    q.x = v.x * v.x; q.y = v.y * v.y; q.z = v.z * v.z; q.w = v.w * v.w;
    float4 s = v;
    s.x += __shfl_xor(s.x, 32, 64); s.y += __shfl_xor(s.y, 32, 64);
    s.z += __shfl_xor(s.z, 32, 64); s.w += __shfl_xor(s.w, 32, 64);
    q.x += __shfl_xor(q.x, 32, 64); q.y += __shfl_xor(q.y, 32, 64);
    q.z += __shfl_xor(q.z, 32, 64); q.w += __shfl_xor(q.w, 32, 64);
    const int lane = tid & 63, wid = tid >> 6;
    if (lane < 32) { redS[wid][lane] = s; redQ[wid][lane] = q; }
    __syncthreads();
    if (tid < 32) {
      float4 S = redS[0][tid];
      float4 Q = redQ[0][tid];
#pragma unroll
      for (int w2 = 1; w2 < 4; ++w2) {
        S.x += redS[w2][tid].x; S.y += redS[w2][tid].y;
        S.z += redS[w2][tid].z; S.w += redS[w2][tid].w;
        Q.x += redQ[w2][tid].x; Q.y += redQ[w2][tid].y;
        Q.z += redQ[w2][tid].z; Q.w += redQ[w2][tid].w;
      }
      atomicAdd(&stats[tid * 4 + 0], S.x); atomicAdd(&stats[tid * 4 + 1], S.y);
      atomicAdd(&stats[tid * 4 + 2], S.z); atomicAdd(&stats[tid * 4 + 3], S.w);
      atomicAdd(&stats[128 + tid * 4 + 0], Q.x); atomicAdd(&stats[128 + tid * 4 + 1], Q.y);
      atomicAdd(&stats[128 + tid * 4 + 2], Q.z); atomicAdd(&stats[128 + tid * 4 + 3], Q.w);
    }
  }
}

// ---------- BN finalize: scale/shift from accumulated stats ----------
__global__ void bn_fin(const float* __restrict__ stats, const float* __restrict__ gamma,
                       const float* __restrict__ beta, float* __restrict__ ss) {
  int f = threadIdx.x;
  float mu = stats[f] * (1.0f / (float)NN);
  float ex2 = stats[128 + f] * (1.0f / (float)NN);
  float var = ex2 - mu * mu;
  float sc = gamma[f] * rsqrtf(var + 1e-5f);
  ss[f] = sc;
  ss[128 + f] = beta[f] - mu * sc;
}

extern "C" void kernel_launch(void* const* d_in, const int* in_sizes, int n_in,
                              void* d_out, int out_size, void* d_ws, size_t ws_size,
                              hipStream_t stream) {
  (void)in_sizes; (void)n_in; (void)out_size; (void)ws_size;
  const float* x   = (const float*)d_in[0];
  const int*   ei  = (const int*)d_in[1];
  const float* ew  = (const float*)d_in[2];
  const float* Wl0 = (const float*)d_in[3];
  const float* Wr0 = (const float*)d_in[4];
  const float* b0  = (const float*)d_in[5];
  const float* Wl1 = (const float*)d_in[6];
  const float* Wr1 = (const float*)d_in[7];
  const float* b1  = (const float*)d_in[8];
  const float* Wl2 = (const float*)d_in[9];
  const float* Wr2 = (const float*)d_in[10];
  const float* b2  = (const float*)d_in[11];
  const float* g0  = (const float*)d_in[12];
  const float* be0 = (const float*)d_in[13];
  const float* g1  = (const float*)d_in[14];
  const float* be1 = (const float*)d_in[15];
  float* out = (float*)d_out;

  size_t off = 0;
  auto alloc = [&](size_t b) -> void* {
    void* p = (char*)d_ws + off;
    off += (b + 255) & ~(size_t)255;
    return p;
  };
  float* tl    = (float*)alloc((size_t)NN * 128 * 4);   // 25.6 MB
  float* tr    = (float*)alloc((size_t)NN * 128 * 4);   // 25.6 MB
  float* hpre  = (float*)alloc((size_t)NN * 128 * 4);   // 25.6 MB
  int2*  esw   = (int2*)alloc((size_t)EE * 8);          // 4.8 MB
  int*   rs    = (int*)alloc((size_t)(NN + 1) * 4);
  int*   cur   = (int*)alloc((size_t)NN * 4);
  float* stats = (float*)alloc(256 * 4);
  float* ssb   = (float*)alloc(256 * 4);

  // CSR build (per call; inputs are re-poisoned each launch)
  hipMemsetAsync(cur, 0, (size_t)NN * 4, stream);
  count_k<<<(EE + 255) / 256, 256, 0, stream>>>(ei, cur);
  scan_k<<<1, 1024, 0, stream>>>(cur, rs);
  hipMemcpyAsync(cur, rs, (size_t)NN * 4, hipMemcpyDeviceToDevice, stream);
  fill_k<<<(EE + 255) / 256, 256, 0, stream>>>(ei, ew, cur, esw);

  // layer 0: input x, no BN on input
  gemm_dual<128><<<(NN + 63) / 64, 256, 0, stream>>>(x, Wl0, Wr0, nullptr, tl, tr);
  hipMemsetAsync(stats, 0, 256 * 4, stream);
  gather_combine<32, true><<<NN / 8, 256, 0, stream>>>(tl, tr, rs, esw, b0, hpre, stats);
  bn_fin<<<1, 128, 0, stream>>>(stats, g0, be0, ssb);

  // layer 1: BN0+ReLU folded into GEMM staging
  gemm_dual<128><<<(NN + 63) / 64, 256, 0, stream>>>(hpre, Wl1, Wr1, ssb, tl, tr);
  hipMemsetAsync(stats, 0, 256 * 4, stream);
  gather_combine<32, true><<<NN / 8, 256, 0, stream>>>(tl, tr, rs, esw, b1, hpre, stats);
  bn_fin<<<1, 128, 0, stream>>>(stats, g1, be1, ssb);

  // layer 2: BN1+ReLU folded into GEMM staging, output F=64 straight to d_out
  gemm_dual<64><<<(NN + 127) / 128, 256, 0, stream>>>(hpre, Wl2, Wr2, ssb, tl, tr);
  gather_combine<16, false><<<NN / 16, 256, 0, stream>>>(tl, tr, rs, esw, b2, out, nullptr);
}